// Round 1
// 78.777 us; speedup vs baseline: 1.0062x; 1.0062x over previous
//
#include <hip/hip_runtime.h>

// SLayer RBF pooling: out[b,n] = sum_p mask[b,p] * exp(-(s0*(c0-x0)^2 + s1*(c1-x1)^2))
// B=64, P=16384, N=64, D=2.
//
// Structure: lane = center index n (one accumulator per lane). Points staged in
// LDS *verbatim interleaved* and read as float4 (ds_read_b128 wave-uniform
// broadcast, conflict-free) -> 3 LDS instructions per 4 points instead of 12.
// exp(-e) computed as exp2(t) with -log2(e) folded into per-n coefficients:
// t = A + x0*(C0*x0+B0) + x1*(C1*x1+B1)  (4 FMAs + 1 exp2 + 1 acc-FMA per pair).
//
// kernel_launch: zero ONLY the B*N floats we accumulate into (16 KB). The
// harness d_out allocation is 268 MB; memsetting all of it was a 42 us
// fillBufferAligned inside the timed graph -- more than the kernel itself.

#if __has_builtin(__builtin_amdgcn_exp2f)
#define EXP2(x) __builtin_amdgcn_exp2f(x)
#else
#define EXP2(x) exp2f(x)
#endif

constexpr int BATCH  = 64;
constexpr int P      = 16384;
constexpr int N      = 64;
constexpr int CHUNKS = 16;            // point-chunks per batch
constexpr int CHUNK  = P / CHUNKS;    // 1024 points per block
constexpr int BLOCK  = 256;           // 4 waves
constexpr int WPTS   = CHUNK / 4;     // 256 points per wave

__global__ __launch_bounds__(BLOCK) void slayer_rbf(
    const float* __restrict__ batch,
    const float* __restrict__ mask,
    const float* __restrict__ centers,
    const float* __restrict__ sharp,
    float* __restrict__ out)
{
    __shared__ float4 spt[CHUNK / 2];   // batch chunk verbatim (x,y interleaved): 8 KB
    __shared__ float4 smk[CHUNK / 4];   // mask chunk: 4 KB
    __shared__ float  red[4][N];

    const int blk   = blockIdx.x;
    const int b     = blk >> 4;              // / CHUNKS
    const int chunk = blk & (CHUNKS - 1);
    const int tid   = threadIdx.x;

    // ---- stage batch chunk into LDS, verbatim float4 copy (coalesced) ----
    const float4* bp = (const float4*)(batch + ((size_t)b * P + (size_t)chunk * CHUNK) * 2);
    #pragma unroll
    for (int i = tid; i < CHUNK / 2; i += BLOCK)    // 512 float4 = 2048 floats
        spt[i] = bp[i];
    const float4* mp = (const float4*)(mask + (size_t)b * P + (size_t)chunk * CHUNK);
    #pragma unroll
    for (int i = tid; i < CHUNK / 4; i += BLOCK)    // 256 float4 = 1024 floats
        smk[i] = mp[i];

    // ---- per-lane center coefficients (lane = n) ----
    const int lane = tid & 63;
    const float c0 = centers[2 * lane], c1 = centers[2 * lane + 1];
    const float s0 = sharp[2 * lane],  s1 = sharp[2 * lane + 1];
    const float L  = 1.4426950408889634f;     // log2(e)
    const float C0 = -L * s0, C1 = -L * s1;
    const float B0 = -2.0f * C0 * c0, B1 = -2.0f * C1 * c1;
    const float A  = C0 * c0 * c0 + C1 * c1 * c1;
    // t = A + x0*(C0*x0 + B0) + x1*(C1*x1 + B1)  ==  -log2e * expo

    __syncthreads();

    // ---- main loop: each wave sweeps its 256 points, 4 points/iter ----
    // Per iter: 2x ds_read_b128 (4 points, interleaved x,y) + 1x ds_read_b128
    // (4 masks) + 16 FMA + 4 exp2 + 4 acc-FMA. All LDS reads wave-uniform.
    const int wave = tid >> 6;
    const int q0 = wave * (WPTS / 2);   // float4 index into spt (2 points per float4)
    const int m0 = wave * (WPTS / 4);   // float4 index into smk
    float acc0 = 0.f, acc1 = 0.f, acc2 = 0.f, acc3 = 0.f;
    for (int it = 0; it < WPTS / 4; ++it) {
        float4 pa = spt[q0 + 2 * it];
        float4 pb = spt[q0 + 2 * it + 1];
        float4 mm = smk[m0 + it];
        float ta = fmaf(pa.x, fmaf(C0, pa.x, B0), fmaf(pa.y, fmaf(C1, pa.y, B1), A));
        float tb = fmaf(pa.z, fmaf(C0, pa.z, B0), fmaf(pa.w, fmaf(C1, pa.w, B1), A));
        float tc = fmaf(pb.x, fmaf(C0, pb.x, B0), fmaf(pb.y, fmaf(C1, pb.y, B1), A));
        float td = fmaf(pb.z, fmaf(C0, pb.z, B0), fmaf(pb.w, fmaf(C1, pb.w, B1), A));
        acc0 = fmaf(mm.x, EXP2(ta), acc0);
        acc1 = fmaf(mm.y, EXP2(tb), acc1);
        acc2 = fmaf(mm.z, EXP2(tc), acc2);
        acc3 = fmaf(mm.w, EXP2(td), acc3);
    }
    float acc = (acc0 + acc1) + (acc2 + acc3);

    // ---- epilogue: reduce 4 waves, one atomicAdd per (b,n) ----
    red[wave][lane] = acc;
    __syncthreads();
    if (tid < N) {
        float s = red[0][tid] + red[1][tid] + red[2][tid] + red[3][tid];
        atomicAdd(&out[b * N + tid], s);
    }
}

extern "C" void kernel_launch(void* const* d_in, const int* in_sizes, int n_in,
                              void* d_out, int out_size, void* d_ws, size_t ws_size,
                              hipStream_t stream) {
    const float* batch   = (const float*)d_in[0];
    const float* mask    = (const float*)d_in[1];
    const float* centers = (const float*)d_in[2];
    const float* sharp   = (const float*)d_in[3];
    float* out = (float*)d_out;

    // Zero ONLY the accumulated region (B*N floats = 16 KB). d_out's full
    // allocation is ~268 MB; memsetting it all cost 42 us per call.
    hipMemsetAsync(out, 0, (size_t)BATCH * N * sizeof(float), stream);
    slayer_rbf<<<BATCH * CHUNKS, BLOCK, 0, stream>>>(batch, mask, centers, sharp, out);
}